// Round 7
// baseline (195.292 us; speedup 1.0000x reference)
//
#include <hip/hip_runtime.h>

// ---------------------------------------------------------------------------
// keypoint_embedding, R10: dataflow mega-kernel, BK=128 + incremental
// per-chunk dependency waits (software-pipelined stages).
//   R9 post-mortem: e2e = ~78us fixed (poison fill evicts L2 every iter +
//   harness gaps) + kernel. Kernel latency-bound with ~1us per 64-wide
//   K-chunk (2 barriers + cold-miss loads). Fixes:
//   - BK=128: serial chain 30 -> 15 chunks; 8 MFMA + 12 ds_read cover/chunk
//   - chunk j waits only its 2 producer flags (all-thread poll, no barrier)
//   - W loads (8x float4/thread) issue BEFORE the flag wait (inputs)
//   - LDS stride 132 (writes <=4-way, reads 2-way ~free)
// Protocol from R8/R9 kept: sc1 producer stores, entry acquire-fence, cached
// consumer loads, equality-MAGIC flags (poison-immune, no memset).
// ---------------------------------------------------------------------------

typedef __attribute__((ext_vector_type(8))) short s16x8;
typedef __attribute__((ext_vector_type(8))) unsigned short u16x8;
typedef __attribute__((ext_vector_type(4))) float f32x4;

#define NBLK 512
#define MAGIC 0xA5C3961Du
#define LDA 132

static __device__ __forceinline__ unsigned short f2bf(float f) {
    unsigned u = __float_as_uint(f);
    u += 0x7fff + ((u >> 16) & 1);   // round-to-nearest-even
    return (unsigned short)(u >> 16);
}

// packed f32x2 -> bf16x2 (RNE), single VALU op
static __device__ __forceinline__ unsigned cvtpk(float lo, float hi) {
    unsigned r;
    asm("v_cvt_pk_bf16_f32 %0, %1, %2" : "=v"(r) : "v"(lo), "v"(hi));
    return r;
}

// ---- agent-coherent (IC-level, L2-bypass) accessors -----------------------
static __device__ __forceinline__ unsigned agl_u32(const unsigned* p) {
    return __hip_atomic_load(p, __ATOMIC_RELAXED, __HIP_MEMORY_SCOPE_AGENT);
}
static __device__ __forceinline__ void ags_u32(unsigned* p, unsigned v) {
    __hip_atomic_store(p, v, __ATOMIC_RELAXED, __HIP_MEMORY_SCOPE_AGENT);
}
static __device__ __forceinline__ void ags_f32(float* p, float v) {
    __hip_atomic_store(p, v, __ATOMIC_RELAXED, __HIP_MEMORY_SCOPE_AGENT);
}
static __device__ __forceinline__ void ags_u16(unsigned short* p, unsigned short v) {
    __hip_atomic_store(p, v, __ATOMIC_RELAXED, __HIP_MEMORY_SCOPE_AGENT);
}

// Producer: all waves' sc1 data stores drained at the barrier, then flag.
static __device__ __forceinline__ void flag_set(unsigned* f) {
    __syncthreads();
    if (threadIdx.x == 0) ags_u32(f, MAGIC);
}
// All threads poll the two flags covering K-chunk j. The trailing asm is a
// compiler memory barrier: the dependent A-loads cannot hoist above the spin.
static __device__ __forceinline__ void wait2(const unsigned* f, int j) {
    while (agl_u32(&f[2 * j]) != MAGIC)     __builtin_amdgcn_s_sleep(1);
    while (agl_u32(&f[2 * j + 1]) != MAGIC) __builtin_amdgcn_s_sleep(1);
    asm volatile("" ::: "memory");
}

// ---- generic MFMA GEMM tile, BK=128: C = act(A @ Wf^T + b) ----------------
// 32x64 block tile; W (fp32 input) converted bf16 during LDS staging.
// wgather: W row r maps to w1[(r&511)*2048 + (r>>9)*1024 + k] (A|B split).
// fdep: row-group flag base; chunk j needs fdep[2j], fdep[2j+1].
static __device__ void gemm_stage(
    char* smem, int K, int tn, int wgather,
    const unsigned short* __restrict__ A,
    const float* __restrict__ Wf,
    const float* __restrict__ bias, int relu,
    unsigned short* __restrict__ Cb, float* __restrict__ Cf, int N,
    const unsigned* __restrict__ fdep, unsigned* __restrict__ fout)
{
    unsigned short* As = (unsigned short*)smem;                  // 32 x LDA
    unsigned short* Ws = (unsigned short*)(smem + 32 * LDA * 2); // 64 x LDA
    int t = threadIdx.x;
    int tile = blockIdx.x;
    int m0 = (tile / tn) * 32, n0 = (tile % tn) * 64;
    int lane = t & 63, wv = t >> 6;
    int wm = (wv >> 1) * 16, wn = (wv & 1) * 32;
    int lr = lane & 15, quad = lane >> 4;

    // staging geometry (BK=128)
    int arow = t >> 3, acol = (t & 7) * 16;      // A: 2 slots/thread
    int wrow = t >> 2, wcol = (t & 3) * 32;      // W: 4 slots/thread
    int gr = n0 + wrow;
    const float* wp = wgather ? Wf + (size_t)(gr & 511) * 2048 + ((size_t)(gr >> 9) << 10)
                              : Wf + (size_t)gr * K;
    const unsigned short* Ap = A + (size_t)(m0 + arow) * K + acol;

    int nch = K >> 7;
    float4 wr[8];
    u16x8 ar0, ar1;

    // chunk 0: W loads first (input, no dep), then flag wait, then A loads
#pragma unroll
    for (int q = 0; q < 8; ++q) wr[q] = *(const float4*)(wp + wcol + q * 4);
    wait2(fdep, 0);
    ar0 = *(const u16x8*)(Ap);
    ar1 = *(const u16x8*)(Ap + 8);

    f32x4 acc[2] = {};
    for (int j = 0; j < nch; ++j) {
        __syncthreads();                       // prior LDS reads done
        {
            union { unsigned u[4]; u16x8 v; } pk;
#pragma unroll
            for (int s = 0; s < 4; ++s) {
                float4 a = wr[2 * s], b = wr[2 * s + 1];
                pk.u[0] = cvtpk(a.x, a.y); pk.u[1] = cvtpk(a.z, a.w);
                pk.u[2] = cvtpk(b.x, b.y); pk.u[3] = cvtpk(b.z, b.w);
                *(u16x8*)(Ws + wrow * LDA + wcol + s * 8) = pk.v;
            }
            *(u16x8*)(As + arow * LDA + acol)     = ar0;
            *(u16x8*)(As + arow * LDA + acol + 8) = ar1;
        }
        __syncthreads();
        if (j + 1 < nch) {                     // 1-deep prefetch
            int ko = (j + 1) << 7;
#pragma unroll
            for (int q = 0; q < 8; ++q) wr[q] = *(const float4*)(wp + ko + wcol + q * 4);
            wait2(fdep, j + 1);
            ar0 = *(const u16x8*)(Ap + ko);
            ar1 = *(const u16x8*)(Ap + ko + 8);
        }
#pragma unroll
        for (int kk = 0; kk < 128; kk += 32) {
            s16x8 af  = *(const s16x8*)(As + (wm + lr) * LDA + kk + quad * 8);
            s16x8 bf0 = *(const s16x8*)(Ws + (wn + lr) * LDA + kk + quad * 8);
            s16x8 bf1 = *(const s16x8*)(Ws + (wn + 16 + lr) * LDA + kk + quad * 8);
            acc[0] = __builtin_amdgcn_mfma_f32_16x16x32_bf16(af, bf0, acc[0], 0, 0, 0);
            acc[1] = __builtin_amdgcn_mfma_f32_16x16x32_bf16(af, bf1, acc[1], 0, 0, 0);
        }
    }

#pragma unroll
    for (int nt = 0; nt < 2; ++nt) {
        int col = n0 + wn + nt * 16 + lr;
        float bv = bias ? bias[col] : 0.f;
#pragma unroll
        for (int r = 0; r < 4; ++r) {
            int row = m0 + wm + quad * 4 + r;
            float v = acc[nt][r] + bv;
            if (relu) v = fmaxf(v, 0.f);
            if (Cb) ags_u16(Cb + (size_t)row * N + col, f2bf(v));
            else    ags_f32(Cf + (size_t)row * N + col, v);
        }
    }
    flag_set(fout);
}

// ---- S1: emb0 A-tile in LDS + GEMM with r1w (K=128, single chunk) ---------
static __device__ void stage1(
    char* smem,
    const float* __restrict__ x,
    const float* __restrict__ e1w, const float* __restrict__ e1b,
    const float* __restrict__ e2w, const float* __restrict__ e2b,
    const float* __restrict__ r1w, const float* __restrict__ r1b,
    unsigned short* __restrict__ emb1b, unsigned* __restrict__ f1)
{
    unsigned short* As = (unsigned short*)smem;                  // 32 x LDA
    unsigned short* Ws = (unsigned short*)(smem + 32 * LDA * 2); // 64 x LDA
    int t = threadIdx.x;
    int i = blockIdx.x;
    int m0 = (i >> 2) * 32, n0 = (i & 3) * 64;

    // W loads first (hide under the emb0 VALU work)
    int wrow = t >> 2, wcol = (t & 3) * 32;
    const float* wp = r1w + (size_t)(n0 + wrow) * 128;
    float4 wr[8];
#pragma unroll
    for (int q = 0; q < 8; ++q) wr[q] = *(const float4*)(wp + wcol + q * 4);

    // emb0 tile: thread handles 16 cols of one row
    {
        int row = t >> 3, c0 = (t & 7) * 16;
        const float* xr = x + (size_t)(m0 + row) * 16;
        float4 xv0 = *(const float4*)(xr);
        float4 xv1 = *(const float4*)(xr + 4);
        float4 xv2 = *(const float4*)(xr + 8);
        float4 xv3 = *(const float4*)(xr + 12);
        float xv[16] = {xv0.x, xv0.y, xv0.z, xv0.w, xv1.x, xv1.y, xv1.z, xv1.w,
                        xv2.x, xv2.y, xv2.z, xv2.w, xv3.x, xv3.y, xv3.z, xv3.w};
        union { unsigned u[4]; u16x8 v; } pk0, pk1;
#pragma unroll
        for (int e = 0; e < 16; e += 2) {
            float o2[2];
#pragma unroll
            for (int h = 0; h < 2; ++h) {
                int o = c0 + e + h;
                float s1 = e1b[o] + xv[0] * e1w[o * 3] + xv[1] * e1w[o * 3 + 1]
                                  + xv[2] * e1w[o * 3 + 2];
                float s2 = e2b[o];
#pragma unroll
                for (int k = 0; k < 13; ++k) s2 += xv[3 + k] * e2w[o * 13 + k];
                o2[h] = fmaxf(s1, 0.f) + fmaxf(s2, 0.f);
            }
            unsigned pv = cvtpk(o2[0], o2[1]);
            if (e < 8) pk0.u[e >> 1] = pv; else pk1.u[(e - 8) >> 1] = pv;
        }
        *(u16x8*)(As + row * LDA + c0)     = pk0.v;
        *(u16x8*)(As + row * LDA + c0 + 8) = pk1.v;
    }
    __syncthreads();                           // As complete
    {
        union { unsigned u[4]; u16x8 v; } pk;
#pragma unroll
        for (int s = 0; s < 4; ++s) {
            float4 a = wr[2 * s], b = wr[2 * s + 1];
            pk.u[0] = cvtpk(a.x, a.y); pk.u[1] = cvtpk(a.z, a.w);
            pk.u[2] = cvtpk(b.x, b.y); pk.u[3] = cvtpk(b.z, b.w);
            *(u16x8*)(Ws + wrow * LDA + wcol + s * 8) = pk.v;
        }
    }
    __syncthreads();                           // Ws complete

    int lane = t & 63, wv = t >> 6;
    int wm = (wv >> 1) * 16, wn = (wv & 1) * 32;
    int lr = lane & 15, quad = lane >> 4;
    f32x4 acc[2] = {};
#pragma unroll
    for (int kk = 0; kk < 128; kk += 32) {
        s16x8 af  = *(const s16x8*)(As + (wm + lr) * LDA + kk + quad * 8);
        s16x8 bf0 = *(const s16x8*)(Ws + (wn + lr) * LDA + kk + quad * 8);
        s16x8 bf1 = *(const s16x8*)(Ws + (wn + 16 + lr) * LDA + kk + quad * 8);
        acc[0] = __builtin_amdgcn_mfma_f32_16x16x32_bf16(af, bf0, acc[0], 0, 0, 0);
        acc[1] = __builtin_amdgcn_mfma_f32_16x16x32_bf16(af, bf1, acc[1], 0, 0, 0);
    }

#pragma unroll
    for (int nt = 0; nt < 2; ++nt) {
        int col = n0 + wn + nt * 16 + lr;
        float bv = r1b[col];
#pragma unroll
        for (int r = 0; r < 4; ++r) {
            int row = m0 + wm + quad * 4 + r;
            ags_u16(emb1b + (size_t)row * 256 + col, f2bf(fmaxf(acc[nt][r] + bv, 0.f)));
        }
    }
    flag_set(&f1[i]);
}

// ---- S5: pairwise relu-mean partials --------------------------------------
static __device__ void stage5(
    char* smem,
    const float* __restrict__ AB, const float* __restrict__ b1,
    float* __restrict__ pmsum,
    const unsigned* __restrict__ f4, unsigned* __restrict__ f5)
{
    float* sA  = (float*)smem;                       // 64*64
    float* sB  = (float*)(smem + 16384);             // 16*64
    float* sb1 = (float*)(smem + 20480);             // 64
    float (*sPart)[64] = (float(*)[64])(smem + 20736);   // 4*64
    int u = blockIdx.x;
    int t = threadIdx.x;
    int b = u & 15, cb = (u >> 4) & 7, z = u >> 7;
    int c0 = cb * 64;
    int cl = t & 63, ig = t >> 6;

    if (t < 4) {   // 4 specific S4 tiles: m in {2b,2b+1}, n in {cb, cb+8}
        int m = 2 * b + (t & 1), nn = cb + (t >> 1) * 8;
        while (agl_u32(&f4[m * 16 + nn]) != MAGIC) __builtin_amdgcn_s_sleep(1);
    }
    __syncthreads();

#pragma unroll
    for (int rep = 0; rep < 4; ++rep) {
        int lin = rep * 256 + t;
        int j = lin >> 4, cq = (lin & 15) * 4;
        float4 v = *(const float4*)(AB + (size_t)(b * 64 + j) * 1024 + c0 + cq);
        *(float4*)&sA[j * 64 + cq] = v;
    }
    {
        int i2 = t >> 4, cq = (t & 15) * 4;
        float4 v = *(const float4*)(AB + (size_t)(b * 64 + z * 16 + i2) * 1024 + 512 + c0 + cq);
        *(float4*)&sB[i2 * 64 + cq] = v;
    }
    if (t < 64) sb1[t] = b1[c0 + t];
    __syncthreads();

    float av[64];
#pragma unroll
    for (int j = 0; j < 64; ++j) av[j] = sA[j * 64 + cl];
    float b1c = sb1[cl];
    float s = 0.f;
#pragma unroll
    for (int ii = 0; ii < 4; ++ii) {
        float base = sB[(ig * 4 + ii) * 64 + cl] + b1c;
#pragma unroll
        for (int j = 0; j < 64; ++j) s += fmaxf(base + av[j], 0.f);
    }
    sPart[ig][cl] = s;
    __syncthreads();
    if (t < 64) {
        float tot = sPart[0][t] + sPart[1][t] + sPart[2][t] + sPart[3][t];
        ags_f32(&pmsum[((size_t)(b * 4 + z) * 8 + cb) * 64 + t], tot);
    }
    if (t == 0) {   // same wave as the pmsum stores -> wave vmcnt drain suffices
        asm volatile("s_waitcnt vmcnt(0)" ::: "memory");
        ags_u32(&f5[u], MAGIC);
    }
}

// ---- S6: final projection --------------------------------------------------
static __device__ void stage6(
    char* smem,
    const float* __restrict__ pmsum, const float* __restrict__ w2,
    const float* __restrict__ b2, float* __restrict__ out,
    const unsigned* __restrict__ f5)
{
    float* sm = (float*)smem;                        // 512
    int u = blockIdx.x;                              // < 128
    int t = threadIdx.x;
    int b = u & 15, ob = u >> 4;
    if (t < 32)
        while (agl_u32(&f5[b + 16 * t]) != MAGIC) __builtin_amdgcn_s_sleep(1);
    __syncthreads();
#pragma unroll
    for (int h = 0; h < 2; ++h) {
        int c = h * 256 + t;
        int cb = c >> 6, cl = c & 63;
        float s = 0.f;
#pragma unroll
        for (int z = 0; z < 4; ++z)
            s += pmsum[((size_t)(b * 4 + z) * 8 + cb) * 64 + cl];
        sm[c] = s * (1.f / 4096.f);
    }
    __syncthreads();
    int o = ob * 256 + t;
    const float* wr = w2 + (size_t)o * 512;
    float acc = 0.f;
#pragma unroll 8
    for (int c = 0; c < 512; c += 4) {
        float4 w = *(const float4*)(wr + c);
        acc += sm[c] * w.x + sm[c + 1] * w.y + sm[c + 2] * w.z + sm[c + 3] * w.w;
    }
    out[b * 2048 + o] = acc + b2[o];
}

// ---- the mega-kernel -------------------------------------------------------
__global__ __launch_bounds__(256, 2) void k_mega(
    const float* __restrict__ x,
    const float* __restrict__ e1w, const float* __restrict__ e1b,
    const float* __restrict__ e2w, const float* __restrict__ e2b,
    const float* __restrict__ r1w, const float* __restrict__ r1b,
    const float* __restrict__ r2w, const float* __restrict__ r2b,
    const float* __restrict__ r3w, const float* __restrict__ r3b,
    const float* __restrict__ w1,  const float* __restrict__ b1,
    const float* __restrict__ w2,  const float* __restrict__ b2,
    float* __restrict__ out,
    unsigned short* __restrict__ emb1b, unsigned short* __restrict__ emb2b,
    unsigned short* __restrict__ emb3b,
    float* __restrict__ AB, float* __restrict__ pmsum,
    unsigned* __restrict__ f1, unsigned* __restrict__ f2,
    unsigned* __restrict__ f3, unsigned* __restrict__ f4,
    unsigned* __restrict__ f5)
{
    __shared__ __attribute__((aligned(16))) char smem[32 * LDA * 2 + 64 * LDA * 2];
    int i = blockIdx.x;

    // One-time L1/L2 invalidate: drops stale poison lines so flag-protected
    // plain cached reads are coherent (producers write through to IC).
    if (threadIdx.x == 0)
        __builtin_amdgcn_fence(__ATOMIC_ACQUIRE, "agent");
    __syncthreads();

    // S1: x -> emb1 (1024x256), K=128           [128 tiles]
    if (i < 128)
        stage1(smem, x, e1w, e1b, e2w, e2b, r1w, r1b, emb1b, f1);

    // S2: emb1 -> emb2 (1024x512), K=256 (2ch)  [256 tiles, dep f1/chunk]
    if (i < 256)
        gemm_stage(smem, 256, 8, 0, emb1b, r2w, r2b, 1, emb2b, nullptr, 512,
                   &f1[(i >> 3) * 4], &f2[i]);

    // S3: emb2 -> emb3 (1024x1024), K=512 (4ch) [512 tiles, dep f2/chunk]
    gemm_stage(smem, 512, 16, 0, emb2b, r3w, r3b, 1, emb3b, nullptr, 1024,
               &f2[(i >> 4) * 8], &f3[i]);

    // S4: emb3 -> AB (fp32), K=1024 (8ch)       [512 tiles, dep f3/chunk]
    gemm_stage(smem, 1024, 16, 1, emb3b, w1, nullptr, 0, nullptr, AB, 1024,
               &f3[(i >> 4) * 16], &f4[i]);

    // S5: pairwise relu-mean partials           [512 units, dep: 4x f4]
    stage5(smem, AB, b1, pmsum, f4, f5);

    // S6: final projection                      [128 units, dep: 32x f5]
    if (i < 128)
        stage6(smem, pmsum, w2, b2, out, f5);
}

extern "C" void kernel_launch(void* const* d_in, const int* in_sizes, int n_in,
                              void* d_out, int out_size, void* d_ws, size_t ws_size,
                              hipStream_t stream)
{
    const float* x   = (const float*)d_in[0];
    const float* e1w = (const float*)d_in[1];
    const float* e1b = (const float*)d_in[2];
    const float* e2w = (const float*)d_in[3];
    const float* e2b = (const float*)d_in[4];
    const float* r1w = (const float*)d_in[5];
    const float* r1b = (const float*)d_in[6];
    const float* r2w = (const float*)d_in[7];
    const float* r2b = (const float*)d_in[8];
    const float* r3w = (const float*)d_in[9];
    const float* r3b = (const float*)d_in[10];
    const float* w1  = (const float*)d_in[11];
    const float* b1  = (const float*)d_in[12];
    const float* w2  = (const float*)d_in[13];
    const float* b2  = (const float*)d_in[14];
    float* out = (float*)d_out;

    unsigned short* emb1b = (unsigned short*)d_ws;          // 1024*256
    unsigned short* emb2b = emb1b + 1024 * 256;             // 1024*512
    unsigned short* emb3b = emb2b + 1024 * 512;             // 1024*1024
    float* AB    = (float*)(emb3b + 1024 * 1024);           // 1024*1024 fp32
    float* pmsum = AB + 1024 * 1024;                        // 16*4*8*64 fp32
    unsigned* f1 = (unsigned*)(pmsum + 16 * 4 * 8 * 64);    // 128
    unsigned* f2 = f1 + 128;                                // 256
    unsigned* f3 = f2 + 256;                                // 512
    unsigned* f4 = f3 + 512;                                // 512
    unsigned* f5 = f4 + 512;                                // 512

    k_mega<<<NBLK, 256, 0, stream>>>(
        x, e1w, e1b, e2w, e2b, r1w, r1b, r2w, r2b, r3w, r3b,
        w1, b1, w2, b2, out,
        emb1b, emb2b, emb3b, AB, pmsum, f1, f2, f3, f4, f5);
}

// Round 8
// 186.322 us; speedup vs baseline: 1.0481x; 1.0481x over previous
//
#include <hip/hip_runtime.h>

// ---------------------------------------------------------------------------
// keypoint_embedding, R11: R10's BK=128 software-pipelined dataflow kernel
// with STORM-FREE incremental waits.
//   R10 post-mortem: all-256-thread flag polling => up to 131K sc1 spinners
//   congesting the IC fabric (hbm_gbps halved at same FETCH). Fix: per chunk
//   only threads 0-1 spin (one per flag), then one __syncthreads releases
//   the block before the dependent A-loads. Spinner population back to the
//   R9-proven class (~1K device-wide).
// Kept from R10 (validated by counters): BK=128 (15 serial chunks), LDS
// stride 132 (bank conflicts 1.3M -> 217K), W-loads before the dep wait.
// Protocol from R8/R9: sc1 producer stores + entry acquire-fence + cached
// consumer loads + equality-MAGIC flags (poison-immune, no memset).
// ---------------------------------------------------------------------------

typedef __attribute__((ext_vector_type(8))) short s16x8;
typedef __attribute__((ext_vector_type(8))) unsigned short u16x8;
typedef __attribute__((ext_vector_type(4))) float f32x4;

#define NBLK 512
#define MAGIC 0xA5C3961Du
#define LDA 132

static __device__ __forceinline__ unsigned short f2bf(float f) {
    unsigned u = __float_as_uint(f);
    u += 0x7fff + ((u >> 16) & 1);   // round-to-nearest-even
    return (unsigned short)(u >> 16);
}

// packed f32x2 -> bf16x2 (RNE), single VALU op
static __device__ __forceinline__ unsigned cvtpk(float lo, float hi) {
    unsigned r;
    asm("v_cvt_pk_bf16_f32 %0, %1, %2" : "=v"(r) : "v"(lo), "v"(hi));
    return r;
}

// ---- agent-coherent (IC-level, L2-bypass) accessors -----------------------
static __device__ __forceinline__ unsigned agl_u32(const unsigned* p) {
    return __hip_atomic_load(p, __ATOMIC_RELAXED, __HIP_MEMORY_SCOPE_AGENT);
}
static __device__ __forceinline__ void ags_u32(unsigned* p, unsigned v) {
    __hip_atomic_store(p, v, __ATOMIC_RELAXED, __HIP_MEMORY_SCOPE_AGENT);
}
static __device__ __forceinline__ void ags_f32(float* p, float v) {
    __hip_atomic_store(p, v, __ATOMIC_RELAXED, __HIP_MEMORY_SCOPE_AGENT);
}
static __device__ __forceinline__ void ags_u16(unsigned short* p, unsigned short v) {
    __hip_atomic_store(p, v, __ATOMIC_RELAXED, __HIP_MEMORY_SCOPE_AGENT);
}

// Producer: all waves' sc1 data stores drained at the barrier, then flag.
static __device__ __forceinline__ void flag_set(unsigned* f) {
    __syncthreads();
    if (threadIdx.x == 0) ags_u32(f, MAGIC);
}
// Storm-free chunk wait: threads 0-1 spin (one per flag), barrier releases
// the block. The barrier is also the compiler fence against load hoisting.
static __device__ __forceinline__ void wait2_sync(const unsigned* f, int j) {
    if (threadIdx.x < 2)
        while (agl_u32(&f[2 * j + threadIdx.x]) != MAGIC)
            __builtin_amdgcn_s_sleep(1);
    __syncthreads();
}

// ---- generic MFMA GEMM tile, BK=128: C = act(A @ Wf^T + b) ----------------
// 32x64 block tile; W (fp32 input) converted bf16 during LDS staging.
// wgather: W row r maps to w1[(r&511)*2048 + (r>>9)*1024 + k] (A|B split).
// fdep: row-group flag base; chunk j needs fdep[2j], fdep[2j+1].
static __device__ void gemm_stage(
    char* smem, int K, int tn, int wgather,
    const unsigned short* __restrict__ A,
    const float* __restrict__ Wf,
    const float* __restrict__ bias, int relu,
    unsigned short* __restrict__ Cb, float* __restrict__ Cf, int N,
    const unsigned* __restrict__ fdep, unsigned* __restrict__ fout)
{
    unsigned short* As = (unsigned short*)smem;                  // 32 x LDA
    unsigned short* Ws = (unsigned short*)(smem + 32 * LDA * 2); // 64 x LDA
    int t = threadIdx.x;
    int tile = blockIdx.x;
    int m0 = (tile / tn) * 32, n0 = (tile % tn) * 64;
    int lane = t & 63, wv = t >> 6;
    int wm = (wv >> 1) * 16, wn = (wv & 1) * 32;
    int lr = lane & 15, quad = lane >> 4;

    // staging geometry (BK=128)
    int arow = t >> 3, acol = (t & 7) * 16;      // A: 2 slots/thread
    int wrow = t >> 2, wcol = (t & 3) * 32;      // W: 4 slots/thread
    int gr = n0 + wrow;
    const float* wp = wgather ? Wf + (size_t)(gr & 511) * 2048 + ((size_t)(gr >> 9) << 10)
                              : Wf + (size_t)gr * K;
    const unsigned short* Ap = A + (size_t)(m0 + arow) * K + acol;

    int nch = K >> 7;
    float4 wr[8];
    u16x8 ar0, ar1;

    // chunk 0: W loads first (input, no dep), 2-thread spin + barrier, A loads
#pragma unroll
    for (int q = 0; q < 8; ++q) wr[q] = *(const float4*)(wp + wcol + q * 4);
    wait2_sync(fdep, 0);
    ar0 = *(const u16x8*)(Ap);
    ar1 = *(const u16x8*)(Ap + 8);

    f32x4 acc[2] = {};
    for (int j = 0; j < nch; ++j) {
        __syncthreads();                       // prior LDS reads done
        {
            union { unsigned u[4]; u16x8 v; } pk;
#pragma unroll
            for (int s = 0; s < 4; ++s) {
                float4 a = wr[2 * s], b = wr[2 * s + 1];
                pk.u[0] = cvtpk(a.x, a.y); pk.u[1] = cvtpk(a.z, a.w);
                pk.u[2] = cvtpk(b.x, b.y); pk.u[3] = cvtpk(b.z, b.w);
                *(u16x8*)(Ws + wrow * LDA + wcol + s * 8) = pk.v;
            }
            *(u16x8*)(As + arow * LDA + acol)     = ar0;
            *(u16x8*)(As + arow * LDA + acol + 8) = ar1;
        }
        __syncthreads();                       // staged, LDS visible
        if (j + 1 < nch) {                     // 1-deep prefetch, storm-free
            int ko = (j + 1) << 7;
#pragma unroll
            for (int q = 0; q < 8; ++q) wr[q] = *(const float4*)(wp + ko + wcol + q * 4);
            wait2_sync(fdep, j + 1);
            ar0 = *(const u16x8*)(Ap + ko);
            ar1 = *(const u16x8*)(Ap + ko + 8);
        }
#pragma unroll
        for (int kk = 0; kk < 128; kk += 32) {
            s16x8 af  = *(const s16x8*)(As + (wm + lr) * LDA + kk + quad * 8);
            s16x8 bf0 = *(const s16x8*)(Ws + (wn + lr) * LDA + kk + quad * 8);
            s16x8 bf1 = *(const s16x8*)(Ws + (wn + 16 + lr) * LDA + kk + quad * 8);
            acc[0] = __builtin_amdgcn_mfma_f32_16x16x32_bf16(af, bf0, acc[0], 0, 0, 0);
            acc[1] = __builtin_amdgcn_mfma_f32_16x16x32_bf16(af, bf1, acc[1], 0, 0, 0);
        }
    }

#pragma unroll
    for (int nt = 0; nt < 2; ++nt) {
        int col = n0 + wn + nt * 16 + lr;
        float bv = bias ? bias[col] : 0.f;
#pragma unroll
        for (int r = 0; r < 4; ++r) {
            int row = m0 + wm + quad * 4 + r;
            float v = acc[nt][r] + bv;
            if (relu) v = fmaxf(v, 0.f);
            if (Cb) ags_u16(Cb + (size_t)row * N + col, f2bf(v));
            else    ags_f32(Cf + (size_t)row * N + col, v);
        }
    }
    flag_set(fout);
}

// ---- S1: emb0 A-tile in LDS + GEMM with r1w (K=128, single chunk) ---------
static __device__ void stage1(
    char* smem,
    const float* __restrict__ x,
    const float* __restrict__ e1w, const float* __restrict__ e1b,
    const float* __restrict__ e2w, const float* __restrict__ e2b,
    const float* __restrict__ r1w, const float* __restrict__ r1b,
    unsigned short* __restrict__ emb1b, unsigned* __restrict__ f1)
{
    unsigned short* As = (unsigned short*)smem;                  // 32 x LDA
    unsigned short* Ws = (unsigned short*)(smem + 32 * LDA * 2); // 64 x LDA
    int t = threadIdx.x;
    int i = blockIdx.x;
    int m0 = (i >> 2) * 32, n0 = (i & 3) * 64;

    // W loads first (hide under the emb0 VALU work)
    int wrow = t >> 2, wcol = (t & 3) * 32;
    const float* wp = r1w + (size_t)(n0 + wrow) * 128;
    float4 wr[8];
#pragma unroll
    for (int q = 0; q < 8; ++q) wr[q] = *(const float4*)(wp + wcol + q * 4);

    // emb0 tile: thread handles 16 cols of one row
    {
        int row = t >> 3, c0 = (t & 7) * 16;
        const float* xr = x + (size_t)(m0 + row) * 16;
        float4 xv0 = *(const float4*)(xr);
        float4 xv1 = *(const float4*)(xr + 4);
        float4 xv2 = *(const float4*)(xr + 8);
        float4 xv3 = *(const float4*)(xr + 12);
        float xv[16] = {xv0.x, xv0.y, xv0.z, xv0.w, xv1.x, xv1.y, xv1.z, xv1.w,
                        xv2.x, xv2.y, xv2.z, xv2.w, xv3.x, xv3.y, xv3.z, xv3.w};
        union { unsigned u[4]; u16x8 v; } pk0, pk1;
#pragma unroll
        for (int e = 0; e < 16; e += 2) {
            float o2[2];
#pragma unroll
            for (int h = 0; h < 2; ++h) {
                int o = c0 + e + h;
                float s1 = e1b[o] + xv[0] * e1w[o * 3] + xv[1] * e1w[o * 3 + 1]
                                  + xv[2] * e1w[o * 3 + 2];
                float s2 = e2b[o];
#pragma unroll
                for (int k = 0; k < 13; ++k) s2 += xv[3 + k] * e2w[o * 13 + k];
                o2[h] = fmaxf(s1, 0.f) + fmaxf(s2, 0.f);
            }
            unsigned pv = cvtpk(o2[0], o2[1]);
            if (e < 8) pk0.u[e >> 1] = pv; else pk1.u[(e - 8) >> 1] = pv;
        }
        *(u16x8*)(As + row * LDA + c0)     = pk0.v;
        *(u16x8*)(As + row * LDA + c0 + 8) = pk1.v;
    }
    __syncthreads();                           // As complete
    {
        union { unsigned u[4]; u16x8 v; } pk;
#pragma unroll
        for (int s = 0; s < 4; ++s) {
            float4 a = wr[2 * s], b = wr[2 * s + 1];
            pk.u[0] = cvtpk(a.x, a.y); pk.u[1] = cvtpk(a.z, a.w);
            pk.u[2] = cvtpk(b.x, b.y); pk.u[3] = cvtpk(b.z, b.w);
            *(u16x8*)(Ws + wrow * LDA + wcol + s * 8) = pk.v;
        }
    }
    __syncthreads();                           // Ws complete

    int lane = t & 63, wv = t >> 6;
    int wm = (wv >> 1) * 16, wn = (wv & 1) * 32;
    int lr = lane & 15, quad = lane >> 4;
    f32x4 acc[2] = {};
#pragma unroll
    for (int kk = 0; kk < 128; kk += 32) {
        s16x8 af  = *(const s16x8*)(As + (wm + lr) * LDA + kk + quad * 8);
        s16x8 bf0 = *(const s16x8*)(Ws + (wn + lr) * LDA + kk + quad * 8);
        s16x8 bf1 = *(const s16x8*)(Ws + (wn + 16 + lr) * LDA + kk + quad * 8);
        acc[0] = __builtin_amdgcn_mfma_f32_16x16x32_bf16(af, bf0, acc[0], 0, 0, 0);
        acc[1] = __builtin_amdgcn_mfma_f32_16x16x32_bf16(af, bf1, acc[1], 0, 0, 0);
    }

#pragma unroll
    for (int nt = 0; nt < 2; ++nt) {
        int col = n0 + wn + nt * 16 + lr;
        float bv = r1b[col];
#pragma unroll
        for (int r = 0; r < 4; ++r) {
            int row = m0 + wm + quad * 4 + r;
            ags_u16(emb1b + (size_t)row * 256 + col, f2bf(fmaxf(acc[nt][r] + bv, 0.f)));
        }
    }
    flag_set(&f1[i]);
}

// ---- S5: pairwise relu-mean partials --------------------------------------
static __device__ void stage5(
    char* smem,
    const float* __restrict__ AB, const float* __restrict__ b1,
    float* __restrict__ pmsum,
    const unsigned* __restrict__ f4, unsigned* __restrict__ f5)
{
    float* sA  = (float*)smem;                       // 64*64
    float* sB  = (float*)(smem + 16384);             // 16*64
    float* sb1 = (float*)(smem + 20480);             // 64
    float (*sPart)[64] = (float(*)[64])(smem + 20736);   // 4*64
    int u = blockIdx.x;
    int t = threadIdx.x;
    int b = u & 15, cb = (u >> 4) & 7, z = u >> 7;
    int c0 = cb * 64;
    int cl = t & 63, ig = t >> 6;

    if (t < 4) {   // 4 specific S4 tiles: m in {2b,2b+1}, n in {cb, cb+8}
        int m = 2 * b + (t & 1), nn = cb + (t >> 1) * 8;
        while (agl_u32(&f4[m * 16 + nn]) != MAGIC) __builtin_amdgcn_s_sleep(1);
    }
    __syncthreads();

#pragma unroll
    for (int rep = 0; rep < 4; ++rep) {
        int lin = rep * 256 + t;
        int j = lin >> 4, cq = (lin & 15) * 4;
        float4 v = *(const float4*)(AB + (size_t)(b * 64 + j) * 1024 + c0 + cq);
        *(float4*)&sA[j * 64 + cq] = v;
    }
    {
        int i2 = t >> 4, cq = (t & 15) * 4;
        float4 v = *(const float4*)(AB + (size_t)(b * 64 + z * 16 + i2) * 1024 + 512 + c0 + cq);
        *(float4*)&sB[i2 * 64 + cq] = v;
    }
    if (t < 64) sb1[t] = b1[c0 + t];
    __syncthreads();

    float av[64];
#pragma unroll
    for (int j = 0; j < 64; ++j) av[j] = sA[j * 64 + cl];
    float b1c = sb1[cl];
    float s = 0.f;
#pragma unroll
    for (int ii = 0; ii < 4; ++ii) {
        float base = sB[(ig * 4 + ii) * 64 + cl] + b1c;
#pragma unroll
        for (int j = 0; j < 64; ++j) s += fmaxf(base + av[j], 0.f);
    }
    sPart[ig][cl] = s;
    __syncthreads();
    if (t < 64) {
        float tot = sPart[0][t] + sPart[1][t] + sPart[2][t] + sPart[3][t];
        ags_f32(&pmsum[((size_t)(b * 4 + z) * 8 + cb) * 64 + t], tot);
    }
    if (t == 0) {   // same wave as the pmsum stores -> wave vmcnt drain suffices
        asm volatile("s_waitcnt vmcnt(0)" ::: "memory");
        ags_u32(&f5[u], MAGIC);
    }
}

// ---- S6: final projection --------------------------------------------------
static __device__ void stage6(
    char* smem,
    const float* __restrict__ pmsum, const float* __restrict__ w2,
    const float* __restrict__ b2, float* __restrict__ out,
    const unsigned* __restrict__ f5)
{
    float* sm = (float*)smem;                        // 512
    int u = blockIdx.x;                              // < 128
    int t = threadIdx.x;
    int b = u & 15, ob = u >> 4;
    if (t < 32)
        while (agl_u32(&f5[b + 16 * t]) != MAGIC) __builtin_amdgcn_s_sleep(1);
    __syncthreads();
#pragma unroll
    for (int h = 0; h < 2; ++h) {
        int c = h * 256 + t;
        int cb = c >> 6, cl = c & 63;
        float s = 0.f;
#pragma unroll
        for (int z = 0; z < 4; ++z)
            s += pmsum[((size_t)(b * 4 + z) * 8 + cb) * 64 + cl];
        sm[c] = s * (1.f / 4096.f);
    }
    __syncthreads();
    int o = ob * 256 + t;
    const float* wr = w2 + (size_t)o * 512;
    float acc = 0.f;
#pragma unroll 8
    for (int c = 0; c < 512; c += 4) {
        float4 w = *(const float4*)(wr + c);
        acc += sm[c] * w.x + sm[c + 1] * w.y + sm[c + 2] * w.z + sm[c + 3] * w.w;
    }
    out[b * 2048 + o] = acc + b2[o];
}

// ---- the mega-kernel -------------------------------------------------------
__global__ __launch_bounds__(256, 2) void k_mega(
    const float* __restrict__ x,
    const float* __restrict__ e1w, const float* __restrict__ e1b,
    const float* __restrict__ e2w, const float* __restrict__ e2b,
    const float* __restrict__ r1w, const float* __restrict__ r1b,
    const float* __restrict__ r2w, const float* __restrict__ r2b,
    const float* __restrict__ r3w, const float* __restrict__ r3b,
    const float* __restrict__ w1,  const float* __restrict__ b1,
    const float* __restrict__ w2,  const float* __restrict__ b2,
    float* __restrict__ out,
    unsigned short* __restrict__ emb1b, unsigned short* __restrict__ emb2b,
    unsigned short* __restrict__ emb3b,
    float* __restrict__ AB, float* __restrict__ pmsum,
    unsigned* __restrict__ f1, unsigned* __restrict__ f2,
    unsigned* __restrict__ f3, unsigned* __restrict__ f4,
    unsigned* __restrict__ f5)
{
    __shared__ __attribute__((aligned(16))) char smem[32 * LDA * 2 + 64 * LDA * 2];
    int i = blockIdx.x;

    // One-time L1/L2 invalidate: drops stale poison lines so flag-protected
    // plain cached reads are coherent (producers write through to IC).
    if (threadIdx.x == 0)
        __builtin_amdgcn_fence(__ATOMIC_ACQUIRE, "agent");
    __syncthreads();

    // S1: x -> emb1 (1024x256), K=128           [128 tiles]
    if (i < 128)
        stage1(smem, x, e1w, e1b, e2w, e2b, r1w, r1b, emb1b, f1);

    // S2: emb1 -> emb2 (1024x512), K=256 (2ch)  [256 tiles, dep f1/chunk]
    if (i < 256)
        gemm_stage(smem, 256, 8, 0, emb1b, r2w, r2b, 1, emb2b, nullptr, 512,
                   &f1[(i >> 3) * 4], &f2[i]);

    // S3: emb2 -> emb3 (1024x1024), K=512 (4ch) [512 tiles, dep f2/chunk]
    gemm_stage(smem, 512, 16, 0, emb2b, r3w, r3b, 1, emb3b, nullptr, 1024,
               &f2[(i >> 4) * 8], &f3[i]);

    // S4: emb3 -> AB (fp32), K=1024 (8ch)       [512 tiles, dep f3/chunk]
    gemm_stage(smem, 1024, 16, 1, emb3b, w1, nullptr, 0, nullptr, AB, 1024,
               &f3[(i >> 4) * 16], &f4[i]);

    // S5: pairwise relu-mean partials           [512 units, dep: 4x f4]
    stage5(smem, AB, b1, pmsum, f4, f5);

    // S6: final projection                      [128 units, dep: 32x f5]
    if (i < 128)
        stage6(smem, pmsum, w2, b2, out, f5);
}

extern "C" void kernel_launch(void* const* d_in, const int* in_sizes, int n_in,
                              void* d_out, int out_size, void* d_ws, size_t ws_size,
                              hipStream_t stream)
{
    const float* x   = (const float*)d_in[0];
    const float* e1w = (const float*)d_in[1];
    const float* e1b = (const float*)d_in[2];
    const float* e2w = (const float*)d_in[3];
    const float* e2b = (const float*)d_in[4];
    const float* r1w = (const float*)d_in[5];
    const float* r1b = (const float*)d_in[6];
    const float* r2w = (const float*)d_in[7];
    const float* r2b = (const float*)d_in[8];
    const float* r3w = (const float*)d_in[9];
    const float* r3b = (const float*)d_in[10];
    const float* w1  = (const float*)d_in[11];
    const float* b1  = (const float*)d_in[12];
    const float* w2  = (const float*)d_in[13];
    const float* b2  = (const float*)d_in[14];
    float* out = (float*)d_out;

    unsigned short* emb1b = (unsigned short*)d_ws;          // 1024*256
    unsigned short* emb2b = emb1b + 1024 * 256;             // 1024*512
    unsigned short* emb3b = emb2b + 1024 * 512;             // 1024*1024
    float* AB    = (float*)(emb3b + 1024 * 1024);           // 1024*1024 fp32
    float* pmsum = AB + 1024 * 1024;                        // 16*4*8*64 fp32
    unsigned* f1 = (unsigned*)(pmsum + 16 * 4 * 8 * 64);    // 128
    unsigned* f2 = f1 + 128;                                // 256
    unsigned* f3 = f2 + 256;                                // 512
    unsigned* f4 = f3 + 512;                                // 512
    unsigned* f5 = f4 + 512;                                // 512

    k_mega<<<NBLK, 256, 0, stream>>>(
        x, e1w, e1b, e2w, e2b, r1w, r1b, r2w, r2b, r3w, r3b,
        w1, b1, w2, b2, out,
        emb1b, emb2b, emb3b, AB, pmsum, f1, f2, f3, f4, f5);
}